// Round 7
// baseline (4852.002 us; speedup 1.0000x reference)
//
#include <hip/hip_runtime.h>
#include <hip/hip_bf16.h>
#include <math.h>

// Seq2seq GRU (r,z,n), H=1024, L=2, S=T=512, V=32000.
// Round 7: XCD-LOCAL CHAINS.
//   gru_persist: 256 WGs x 512 thr (1 WG/CU forced by 8 waves @ <=256 VGPR ->
//   exactly 32 WGs/XCD). Each WG reads HW_REG_XCC_ID and claims a slot:
//     XCD0 -> L0 chain (32 WGs, 32 elem each): Whh@h + precomputed gi (GEMM).
//     XCD1 -> L1 chain: Whh@h + gi^L1 polled from helpers (prefetched).
//     XCD2,3 -> 64 helper WGs: gi^L1_t = Wih^L1 @ h^L0_t + bih into a 256-slot
//               tagged ring (tag encodes phase|t). XCD4-7 idle.
//   Chain step: sliced 2-pair LOCAL poll -> LDS -> barrier -> 12 dots (q-outer)
//   -> butterfly -> gates on 4 lanes/wave -> tagged publish. 1 barrier/step,
//   double-buffered LDS. All spins bounded -> NaN (visible, never hangs).
// Then: gemm (f32 SIMT; tagged-A variant reads D1 directly) + log-softmax.

#define HID 1024
#define NSTEP 512
#define VOCAB 32000
#define SPIN_LIMIT 20000
typedef unsigned long long u64;
typedef unsigned int u32;

__device__ __forceinline__ u64 ald(const u64* p) {
    return __hip_atomic_load(p, __ATOMIC_RELAXED, __HIP_MEMORY_SCOPE_AGENT);
}
__device__ __forceinline__ void ast(u64* p, u64 v) {
    __hip_atomic_store(p, v, __ATOMIC_RELAXED, __HIP_MEMORY_SCOPE_AGENT);
}
__device__ __forceinline__ u64 pack_hv(float v, u32 tag) {
    return ((u64)tag << 32) | (u64)__float_as_uint(v);
}
__device__ __forceinline__ float payload(u64 v) {
    return __uint_as_float((u32)(v & 0xffffffffu));
}
__device__ __forceinline__ float sel4(float a, float b, float c, float d, int j) {
    float ab = (j & 1) ? b : a;
    float cd = (j & 1) ? d : c;
    return (j & 2) ? cd : ab;
}
__device__ __forceinline__ float sel6(float a, float b, float c, float d, float e,
                                      float f, int j) {
    float s01 = (j & 1) ? b : a;
    float s23 = (j & 1) ? d : c;
    float s45 = (j & 1) ? f : e;
    float s03 = (j & 2) ? s23 : s01;
    return (j & 4) ? s45 : s03;
}

// ---------------------------------------------------------------- embeddings
__global__ __launch_bounds__(256) void gather_embed(
    const int* __restrict__ src_tok, const int* __restrict__ tgt_tok,
    const float* __restrict__ src_emb, const float* __restrict__ tgt_emb,
    float* __restrict__ enc_x, float* __restrict__ dec_x) {
    int b = blockIdx.x, tid = threadIdx.x;
    int tok;
    const float* src;
    float* dst;
    if (b < 512) {
        tok = src_tok[b];
        src = src_emb;
        dst = enc_x + (size_t)b * HID;
    } else {
        int t = b - 512;
        tok = (t == 0) ? 0 : tgt_tok[t - 1];  // BOS = 0
        src = tgt_emb;
        dst = dec_x + (size_t)t * HID;
    }
    float4 v = *(const float4*)(src + (size_t)tok * HID + tid * 4);
    *(float4*)(dst + tid * 4) = v;
}

// ---------------------------------------------------------------- recurrence
__global__ __launch_bounds__(512, 2) void gru_persist(
    const float* __restrict__ gi_e, const float* __restrict__ gi_d,
    const float* __restrict__ eWih, const float* __restrict__ eWhh,
    const float* __restrict__ eBih, const float* __restrict__ eBhh,
    const float* __restrict__ dWih, const float* __restrict__ dWhh,
    const float* __restrict__ dBih, const float* __restrict__ dBhh,
    u64* H0, u64* H1, u64* D0, u64* D1, u64* GIH, u32* cnt) {
    const int tid = threadIdx.x;
    const int wave = tid >> 6, lane = tid & 63;

    __shared__ int s_xcc, s_slot;
    __shared__ __align__(16) float xbuf[2][HID];

    if (tid == 0) {
        u32 xcc = (u32)__builtin_amdgcn_s_getreg((31u << 11) | 20u) & 7u;  // XCC_ID
        s_xcc = (int)xcc;
        s_slot = (int)atomicAdd(&cnt[xcc], 1u);
    }
    __syncthreads();
    const int xcc = s_xcc, slot = s_slot;

    // role decode (spillover keeps coverage if XCC_ID degenerates; dups benign)
    int role = -1, rs = 0;  // 0=L0 chain, 1=L1 chain, 2=helper
    if (xcc == 0) {
        if (slot < 32) { role = 0; rs = slot; }
        else if (slot < 64) { role = 1; rs = slot - 32; }
        else if (slot < 128) { role = 2; rs = slot - 64; }
    } else if (xcc == 1) {
        if (slot < 32) { role = 1; rs = slot; }
        else if (slot < 64) { role = 0; rs = slot - 32; }
        else if (slot < 128) { role = 2; rs = slot - 64; }
    } else if (xcc == 2) {
        if (slot < 32) { role = 2; rs = slot; }
    } else if (xcc == 3) {
        if (slot < 32) { role = 2; rs = 32 + slot; }
    }
    if (role < 0) return;

    if (role < 2) {
        // ================= chain (32 WGs, 32 elements each; wave owns 4) ====
        const int j0 = rs * 32;
        const int jw = j0 + wave * 4;
        const int je = jw + (lane & 3);
        float wreg[12][16];
        float hprev = 0.f;

#pragma unroll 1
        for (int p = 0; p < 2; ++p) {
            const float* Whh = (p ? dWhh : eWhh) + (size_t)role * 3 * HID * HID;
            const float* bhh = (p ? dBhh : eBhh) + (size_t)role * 3 * HID;
            u64* hch = p ? (role ? D1 : D0) : (role ? H1 : H0);
            const u32 tagOut = p ? (role ? 4u : 3u) : (role ? 2u : 1u);
            u64* prevch = role ? H1 : H0;
            const u32 tagPrev = role ? 2u : 1u;
            const float* gilin = p ? gi_d : gi_e;  // role 0 only

            // stage 12 Whh rows/wave into registers
#pragma unroll
            for (int g = 0; g < 3; ++g)
#pragma unroll
                for (int jj = 0; jj < 4; ++jj) {
                    const float* base = Whh + (size_t)(g * HID + jw + jj) * HID;
#pragma unroll
                    for (int q = 0; q < 16; ++q)
                        wreg[g * 4 + jj][q] = base[q * 64 + lane];
                }
            float bR = 0.f, bZ = 0.f, bN = 0.f;
            if (lane < 4) {
                bR = bhh[je];
                bZ = bhh[HID + je];
                bN = bhh[2 * HID + je];
            }

#pragma unroll 1
            for (int t = 0; t < NSTEP; ++t) {
                float* xb = xbuf[t & 1];
                // early gi fetch (overlaps the local h-poll below)
                float g0 = 0.f, g1 = 0.f, g2 = 0.f;
                u64 q0 = 0, q1 = 0, q2 = 0;
                const u32 wantGI = 0x50000000u | ((u32)p << 24) | (u32)t;
                const u64* gp = GIH + (size_t)(t & 255) * 3 * HID + je;
                if (lane < 4) {
                    if (role == 0) {
                        const float* gl = gilin + (size_t)t * 3 * HID + je;
                        g0 = gl[0]; g1 = gl[HID]; g2 = gl[2 * HID];
                    } else {
                        q0 = ald(gp); q1 = ald(gp + HID); q2 = ald(gp + 2 * HID);
                    }
                }
                // own-chain h_{t-1}: sliced local poll (wave covers q=2w,2w+1)
                {
                    const int qa = 2 * wave, qb = qa + 1;
                    if (t == 0 && p == 0) {
                        xb[qa * 64 + lane] = 0.f;
                        xb[qb * 64 + lane] = 0.f;
                    } else {
                        const u64* src = (t > 0) ? (hch + (size_t)(t - 1) * HID)
                                                 : (prevch + (size_t)(NSTEP - 1) * HID);
                        const u32 want = (t > 0) ? tagOut : tagPrev;
                        const u64* pa = src + qa * 64 + lane;
                        const u64* pb = src + qb * 64 + lane;
                        u64 va, vb;
                        int it = 0;
                        for (;;) {
                            va = ald(pa);
                            vb = ald(pb);
                            if ((u32)(va >> 32) == want && (u32)(vb >> 32) == want) break;
                            if (++it >= SPIN_LIMIT) { va = vb = 0x7fc00000u; break; }
                        }
                        xb[qa * 64 + lane] = payload(va);
                        xb[qb * 64 + lane] = payload(vb);
                    }
                }
                __syncthreads();

                float part[12] = {0.f, 0.f, 0.f, 0.f, 0.f, 0.f,
                                  0.f, 0.f, 0.f, 0.f, 0.f, 0.f};
#pragma unroll
                for (int q = 0; q < 16; ++q) {
                    float vq = xb[q * 64 + lane];
#pragma unroll
                    for (int rr = 0; rr < 12; ++rr)
                        part[rr] = fmaf(wreg[rr][q], vq, part[rr]);
                }
#pragma unroll
                for (int off = 1; off < 64; off <<= 1)
#pragma unroll
                    for (int rr = 0; rr < 12; ++rr)
                        part[rr] += __shfl_xor(part[rr], off);

                if (lane < 4) {
                    const int jj = lane;
                    float hr = sel4(part[0], part[1], part[2], part[3], jj) + bR;
                    float hz = sel4(part[4], part[5], part[6], part[7], jj) + bZ;
                    float hn = sel4(part[8], part[9], part[10], part[11], jj) + bN;
                    float gir, giz, gin;
                    if (role == 0) {
                        gir = g0; giz = g1; gin = g2;
                    } else {
                        int it = 0;
                        while ((u32)(q0 >> 32) != wantGI || (u32)(q1 >> 32) != wantGI ||
                               (u32)(q2 >> 32) != wantGI) {
                            if (++it >= SPIN_LIMIT) { q0 = q1 = q2 = 0x7fc00000u; break; }
                            q0 = ald(gp); q1 = ald(gp + HID); q2 = ald(gp + 2 * HID);
                        }
                        gir = payload(q0); giz = payload(q1); gin = payload(q2);
                    }
                    float rg = 1.f / (1.f + __expf(-(gir + hr)));
                    float zg = 1.f / (1.f + __expf(-(giz + hz)));
                    float na = gin + rg * hn;
                    float ng = 2.f / (1.f + __expf(-2.f * na)) - 1.f;  // tanh
                    float hnew = (1.f - zg) * ng + zg * hprev;
                    hprev = hnew;
                    ast(hch + (size_t)t * HID + je, pack_hv(hnew, tagOut));
                }
                // no trailing barrier: double-buffered xbuf + 1 barrier/step is safe
            }
        }
    } else {
        // ================= helper (64 WGs x 48 rows of Wih^L1) ==============
        const int mb = rs * 48;
        float wreg[6][16];
#pragma unroll 1
        for (int p = 0; p < 2; ++p) {
            const float* Wih1 = (p ? dWih : eWih) + (size_t)3 * HID * HID;  // layer 1
            const float* bih1 = (p ? dBih : eBih) + 3 * HID;
            const u64* srcc = p ? D0 : H0;
            const u32 wantH = p ? 3u : 1u;
#pragma unroll
            for (int rr = 0; rr < 6; ++rr) {
                int m = mb + wave * 6 + rr;
                const float* base = Wih1 + (size_t)m * HID;
#pragma unroll
                for (int q = 0; q < 16; ++q) wreg[rr][q] = base[q * 64 + lane];
            }
            float bi = 0.f;
            if (lane < 6) bi = bih1[mb + wave * 6 + lane];

#pragma unroll 1
            for (int t = 0; t < NSTEP; ++t) {
                float* xb = xbuf[t & 1];
                const int qa = 2 * wave, qb = qa + 1;
                const u64* pa = srcc + (size_t)t * HID + qa * 64 + lane;
                const u64* pb = srcc + (size_t)t * HID + qb * 64 + lane;
                u64 va, vb;
                int it = 0;
                for (;;) {
                    va = ald(pa);
                    vb = ald(pb);
                    if ((u32)(va >> 32) == wantH && (u32)(vb >> 32) == wantH) break;
                    if (++it >= SPIN_LIMIT) { va = vb = 0x7fc00000u; break; }
                    __builtin_amdgcn_s_sleep(8);  // throttle remote poll traffic
                }
                xb[qa * 64 + lane] = payload(va);
                xb[qb * 64 + lane] = payload(vb);
                __syncthreads();

                float part[6] = {0.f, 0.f, 0.f, 0.f, 0.f, 0.f};
#pragma unroll
                for (int q = 0; q < 16; ++q) {
                    float vq = xb[q * 64 + lane];
#pragma unroll
                    for (int rr = 0; rr < 6; ++rr)
                        part[rr] = fmaf(wreg[rr][q], vq, part[rr]);
                }
#pragma unroll
                for (int off = 1; off < 64; off <<= 1)
#pragma unroll
                    for (int rr = 0; rr < 6; ++rr)
                        part[rr] += __shfl_xor(part[rr], off);

                if (lane < 6) {
                    int m = mb + wave * 6 + lane;
                    float val = sel6(part[0], part[1], part[2], part[3], part[4],
                                     part[5], lane) + bi;
                    ast(GIH + (size_t)(t & 255) * 3 * HID + m,
                        pack_hv(val, 0x50000000u | ((u32)p << 24) | (u32)t));
                }
            }
        }
    }
}

// ---------------------------------------------------------------- GEMM
// C[i][v] = sum_k A[i][k]*B[v][k] + bias[v]. ATAG=1: A is tagged u64 (low32=f32).
template <int ATAG>
__global__ __launch_bounds__(256) void gemm_k(
    const void* __restrict__ Ap, const float* __restrict__ B,
    const float* __restrict__ bias, float* __restrict__ C, int ldc) {
    const int tid = threadIdx.x;
    const int bi = blockIdx.x;
    const int bv = blockIdx.y;
    const int i0 = bi * 64, v0 = bv * 128;
    __shared__ __align__(16) float As[32 * 68];
    __shared__ __align__(16) float Bs[32 * 132];
    const int tr = tid >> 4, tc = tid & 15;
    float c[4][8] = {};

    for (int kk = 0; kk < HID; kk += 32) {
#pragma unroll
        for (int q = 0; q < 2; q++) {
            int id = tid * 2 + q;  // 0..511
            int r = id >> 3, kq = id & 7;
            float4 a;
            if constexpr (ATAG) {
                const u64* Au = (const u64*)Ap + (size_t)(i0 + r) * HID + kk + kq * 4;
                a = make_float4(payload(Au[0]), payload(Au[1]), payload(Au[2]),
                                payload(Au[3]));
            } else {
                a = *(const float4*)((const float*)Ap + (size_t)(i0 + r) * HID + kk +
                                     kq * 4);
            }
            As[(kq * 4 + 0) * 68 + r] = a.x;
            As[(kq * 4 + 1) * 68 + r] = a.y;
            As[(kq * 4 + 2) * 68 + r] = a.z;
            As[(kq * 4 + 3) * 68 + r] = a.w;
        }
#pragma unroll
        for (int q = 0; q < 4; q++) {
            int id = tid * 4 + q;  // 0..1023
            int vr = id >> 3, kq = id & 7;
            float4 b = *(const float4*)&B[(size_t)(v0 + vr) * HID + kk + kq * 4];
            Bs[(kq * 4 + 0) * 132 + vr] = b.x;
            Bs[(kq * 4 + 1) * 132 + vr] = b.y;
            Bs[(kq * 4 + 2) * 132 + vr] = b.z;
            Bs[(kq * 4 + 3) * 132 + vr] = b.w;
        }
        __syncthreads();
#pragma unroll
        for (int k = 0; k < 32; k++) {
            float4 a4 = *(const float4*)&As[k * 68 + tr * 4];
            float4 b0 = *(const float4*)&Bs[k * 132 + tc * 8];
            float4 b1 = *(const float4*)&Bs[k * 132 + tc * 8 + 4];
            float av[4] = {a4.x, a4.y, a4.z, a4.w};
            float bvv[8] = {b0.x, b0.y, b0.z, b0.w, b1.x, b1.y, b1.z, b1.w};
#pragma unroll
            for (int u = 0; u < 4; u++)
#pragma unroll
                for (int w = 0; w < 8; w++) c[u][w] += av[u] * bvv[w];
        }
        __syncthreads();
    }
    float4 bb0 = *(const float4*)&bias[v0 + tc * 8];
    float4 bb1 = *(const float4*)&bias[v0 + tc * 8 + 4];
#pragma unroll
    for (int u = 0; u < 4; u++) {
        int i = i0 + tr * 4 + u;
        float4 o0 = {c[u][0] + bb0.x, c[u][1] + bb0.y, c[u][2] + bb0.z, c[u][3] + bb0.w};
        float4 o1 = {c[u][4] + bb1.x, c[u][5] + bb1.y, c[u][6] + bb1.z, c[u][7] + bb1.w};
        *(float4*)&C[(size_t)i * ldc + v0 + tc * 8] = o0;
        *(float4*)&C[(size_t)i * ldc + v0 + tc * 8 + 4] = o1;
    }
}

// ---------------------------------------------------------------- log-softmax
__global__ __launch_bounds__(256) void log_softmax_inplace(float* __restrict__ C) {
    const int row = blockIdx.x;
    const int tid = threadIdx.x;
    float* p = C + (size_t)row * VOCAB;
    float m = -3.4e38f, s = 0.f;
    for (int idx = tid; idx < VOCAB / 4; idx += 256) {
        float4 x = ((const float4*)p)[idx];
        float xv[4] = {x.x, x.y, x.z, x.w};
#pragma unroll
        for (int u = 0; u < 4; u++) {
            float nm = fmaxf(m, xv[u]);
            s = s * __expf(m - nm) + __expf(xv[u] - nm);
            m = nm;
        }
    }
#pragma unroll
    for (int off = 1; off < 64; off <<= 1) {
        float om = __shfl_xor(m, off);
        float os = __shfl_xor(s, off);
        float nm = fmaxf(m, om);
        s = s * __expf(m - nm) + os * __expf(om - nm);
        m = nm;
    }
    __shared__ float sm[4], ss[4], sL;
    int wv = tid >> 6;
    if ((tid & 63) == 0) { sm[wv] = m; ss[wv] = s; }
    __syncthreads();
    if (tid == 0) {
        float M = sm[0], S = ss[0];
        for (int w = 1; w < 4; w++) {
            float nm = fmaxf(M, sm[w]);
            S = S * __expf(M - nm) + ss[w] * __expf(sm[w] - nm);
            M = nm;
        }
        sL = M + logf(S);
    }
    __syncthreads();
    float L = sL;
    for (int idx = tid; idx < VOCAB / 4; idx += 256) {
        float4 x = ((const float4*)p)[idx];
        x.x -= L; x.y -= L; x.z -= L; x.w -= L;
        ((float4*)p)[idx] = x;
    }
}

// ---------------------------------------------------------------- launcher
extern "C" void kernel_launch(void* const* d_in, const int* in_sizes, int n_in,
                              void* d_out, int out_size, void* d_ws, size_t ws_size,
                              hipStream_t stream) {
    const int* src_tok = (const int*)d_in[0];
    const int* tgt_tok = (const int*)d_in[1];
    const float* src_emb = (const float*)d_in[2];
    const float* tgt_emb = (const float*)d_in[3];
    const float* eWih = (const float*)d_in[4];
    const float* eWhh = (const float*)d_in[5];
    const float* eBih = (const float*)d_in[6];
    const float* eBhh = (const float*)d_in[7];
    const float* dWih = (const float*)d_in[8];
    const float* dWhh = (const float*)d_in[9];
    const float* dBih = (const float*)d_in[10];
    const float* dBhh = (const float*)d_in[11];
    const float* out_W = (const float*)d_in[12];
    const float* out_b = (const float*)d_in[13];
    float* out = (float*)d_out;

    char* ws = (char*)d_ws;
    // layout (MiB): enc_x 0-2 | dec_x 2-4 | H0 4-8 | H1 8-12 | D0 12-16 |
    //   D1 16-20 | GIH ring 20-26 | cnt @26 | gi_e 27-33 | gi_d 33-39
    float* enc_x = (float*)(ws);
    float* dec_x = (float*)(ws + (2ull << 20));
    u64* H0 = (u64*)(ws + (4ull << 20));
    u64* H1 = (u64*)(ws + (8ull << 20));
    u64* D0 = (u64*)(ws + (12ull << 20));
    u64* D1 = (u64*)(ws + (16ull << 20));
    u64* GIH = (u64*)(ws + (20ull << 20));
    u32* cnt = (u32*)(ws + (26ull << 20));
    float* gi_e = (float*)(ws + (27ull << 20));
    float* gi_d = (float*)(ws + (33ull << 20));

    // Zero all tagged buffers + GIH ring + role counters every launch.
    hipMemsetAsync(ws + (4ull << 20), 0, 23ull << 20, stream);

    gather_embed<<<1024, 256, 0, stream>>>(src_tok, tgt_tok, src_emb, tgt_emb,
                                           enc_x, dec_x);
    // gi = Wih_l0 @ x + bih_l0 for both chains (teacher-forced x is static).
    gemm_k<0><<<dim3(8, 24), 256, 0, stream>>>(enc_x, eWih, eBih, gi_e, 3 * HID);
    gemm_k<0><<<dim3(8, 24), 256, 0, stream>>>(dec_x, dWih, dBih, gi_d, 3 * HID);

    gru_persist<<<256, 512, 0, stream>>>(gi_e, gi_d, eWih, eWhh, eBih, eBhh,
                                         dWih, dWhh, dBih, dBhh, H0, H1, D0, D1,
                                         GIH, cnt);

    gemm_k<1><<<dim3(8, 250), 256, 0, stream>>>(D1, out_W, out_b, out, VOCAB);
    log_softmax_inplace<<<512, 256, 0, stream>>>(out);
}